// Round 10
// baseline (212.206 us; speedup 1.0000x reference)
//
#include <hip/hip_runtime.h>

// ---- problem constants (fixed by reference setup_inputs) ----
constexpr int B_  = 32;
constexpr int Na  = 512;
constexpr int Nv  = 256;
constexpr int D   = 384;

constexpr int BK  = 32;        // k-chunk per iteration
constexpr int BN  = 64;        // audio rows per block (one n-chunk)
constexpr int NK  = D / BK;    // 12 k-iters
constexpr int NCH = Na / BN;   // 8 n-chunks -> grid = 32*32*8

// swizzled units: 1 unit = 64 lanes x 16 B = 1 KB, lane-linear
constexpr int AUNITS = B_ * NCH * 4 * NK * 64;      // 786,432 (12.58 MB)
constexpr int BUNITS = B_ * NK * 16 * 64;           // 393,216 (6.29 MB)
constexpr int TUNITS = AUNITS + BUNITS;             // 1,179,648

typedef short  bf16x8  __attribute__((ext_vector_type(8)));
typedef float  floatx4 __attribute__((ext_vector_type(4)));
typedef unsigned short ushort8v __attribute__((ext_vector_type(8)));

// fp32 -> bf16 round-to-nearest-even
__device__ __forceinline__ unsigned short f2bf(float f) {
    unsigned int u = __float_as_uint(f);
    u += 0x7fffu + ((u >> 16) & 1u);
    return (unsigned short)(u >> 16);
}

// 16B-per-lane async global->LDS (lane i writes LDS slot base + i*16)
__device__ __forceinline__ void async_load16(const void* g, void* l) {
    __builtin_amdgcn_global_load_lds(
        (const __attribute__((address_space(1))) unsigned int*)g,
        (__attribute__((address_space(3))) unsigned int*)l,
        16, 0, 0);
}

// ---- K1: zero output + fp32 -> bf16 conversion into FRAGMENT-SWIZZLED layout ----
// ONE unit-slot (16 B) per thread, 4608 blocks — pure latency-parallel, no
// grid-stride serialization (the round-9 convert was ~3x slower than its
// memory floor on 4.5 serial dependent units/thread).
// A unit u = ((bi*8+nc8)*4+uq)*12+k  (lane l): A[bi][nc8*64+uq*16+(l&15)][k*32+(l>>4)*8..+8)
// B unit u = (bj*12+k)*16+wq        (lane l): V[bj][wq*16+(l&15)][k*32+(l>>4)*8..+8)
__global__ void convert_swizzle_kernel(const float* __restrict__ a, const float* __restrict__ v,
                                       unsigned short* __restrict__ asw,
                                       unsigned short* __restrict__ bsw,
                                       float* __restrict__ out) {
    int u = blockIdx.x * blockDim.x + threadIdx.x;
    if (u < B_ * B_) out[u] = 0.0f;    // d_out is poisoned before every launch
    if (u >= TUNITS) return;
    const float* srcp;
    unsigned short* dst;
    if (u < AUNITS) {
        int l = u & 63;
        int t = u >> 6;
        int k   = t % 12;  t /= 12;
        int uq  = t & 3;   t >>= 2;
        int nc8 = t & 7;   t >>= 3;
        int bi  = t;
        int row = bi * Na + nc8 * BN + uq * 16 + (l & 15);
        int kel = k * BK + (l >> 4) * 8;
        srcp = a + (size_t)row * D + kel;
        dst  = asw + (size_t)u * 8;
    } else {
        int u2 = u - AUNITS;
        int l = u2 & 63;
        int t = u2 >> 6;
        int wq = t & 15;  t >>= 4;
        int k  = t % 12;
        int bj = t / 12;
        int row = bj * Nv + wq * 16 + (l & 15);
        int kel = k * BK + (l >> 4) * 8;
        srcp = v + (size_t)row * D + kel;
        dst  = bsw + (size_t)u2 * 8;
    }
    float4 f0 = ((const float4*)srcp)[0];
    float4 f1 = ((const float4*)srcp)[1];
    ushort8v o = { f2bf(f0.x), f2bf(f0.y), f2bf(f0.z), f2bf(f0.w),
                   f2bf(f1.x), f2bf(f1.y), f2bf(f1.z), f2bf(f1.w) };
    *(ushort8v*)dst = o;
}

// ---- K2: fused bf16 GEMM + logsumexp-pool ----
// Block-tile 64x256, wave-tile 32x128, acc = 64 regs/wave, 4 blocks/CU.
// B: ring-2 LDS via global_load_lds, depth-1 prefetch, __syncthreads per iter.
// A: straight from swizzled global into regs, distance-1 prefetch.
// Inner loop reads B-frags in 4-deep bursts (explicit ILP for lgkmcnt
// scheduling). Epilogue: LSE WITHOUT max-subtraction — |sims/tau| <= ~55 so
// exp2 stays within fp32 range (max ~3e23, sum ~1e26 << 3.4e38); exact in
// fp32, halves epilogue transcendentals and shuffles.
__global__ __launch_bounds__(256, 4) void gemm_lse_kernel(
        const unsigned short* __restrict__ asw,
        const unsigned short* __restrict__ bsw,
        float* __restrict__ out)
{
    __shared__ unsigned short blds[2][Nv * BK];   // 2 x 16 KB
    __shared__ float ms[BN][2];                   // [row][colhalf] partial sums

    // hierarchical decode: any 1024-consecutive-bid window = 8 bi x 16 bj x 8 nc
    int t = blockIdx.x;
    const int nc8   = t & 7;          t >>= 3;
    const int bj_lo = t & 15;         t >>= 4;
    const int bi_lo = t & 7;          t >>= 3;
    const int bj_hi = t & 1;          t >>= 1;
    const int bi    = t * 8 + bi_lo;
    const int bj    = bj_hi * 16 + bj_lo;

    const int tid  = threadIdx.x;
    const int lane = tid & 63;
    const int wave = tid >> 6;
    const int fr   = lane & 15;
    const int g    = lane >> 4;
    const int rh   = wave >> 1;    // row half (0: rows 0-31, 1: rows 32-63)
    const int ch   = wave & 1;     // col half (0: cols 0-127, 1: cols 128-255)

    // wave-uniform base offsets (stay in SGPRs) + one per-lane byte offset
    const size_t laneoff = (size_t)lane * 16;                       // bytes
    const char* abase = (const char*)asw
        + (size_t)(((bi * 8 + nc8) * 4 + rh * 2) * 12) * 1024;      // frag af adds af*12*1024
    const char* bbase = (const char*)bsw
        + (size_t)((bj * 12) * 16 + wave * 4) * 1024;               // unit q adds q*1024

    // ---- prologue: issue B[0], load A[0] ----
    #pragma unroll
    for (int q = 0; q < 4; ++q)
        async_load16(bbase + q * 1024 + laneoff,
                     (void*)&blds[0][(wave * 4 + q) * 512]);
    bf16x8 a[2], na[2];
    #pragma unroll
    for (int af = 0; af < 2; ++af)
        a[af] = *(const bf16x8*)(abase + (size_t)af * 12 * 1024 + laneoff);

    floatx4 acc[2][8];
    #pragma unroll
    for (int af = 0; af < 2; ++af)
        #pragma unroll
        for (int mt = 0; mt < 8; ++mt)
            acc[af][mt] = (floatx4){0.f, 0.f, 0.f, 0.f};

    #pragma unroll
    for (int k = 0; k < NK; ++k) {
        __syncthreads();   // drains loads issued one full compute-phase ago

        #pragma unroll
        for (int af = 0; af < 2; ++af) na[af] = a[af];
        if (k + 1 < NK) {
            #pragma unroll
            for (int q = 0; q < 4; ++q)
                async_load16(bbase + (size_t)(k + 1) * 16 * 1024 + q * 1024 + laneoff,
                             (void*)&blds[(k + 1) & 1][(wave * 4 + q) * 512]);
            #pragma unroll
            for (int af = 0; af < 2; ++af)
                na[af] = *(const bf16x8*)(abase + (size_t)af * 12 * 1024
                                          + (size_t)(k + 1) * 1024 + laneoff);
        }

        const unsigned short* buf = blds[k & 1];
        #pragma unroll
        for (int h = 0; h < 2; ++h) {
            bf16x8 bfr[4];
            #pragma unroll
            for (int j = 0; j < 4; ++j)
                bfr[j] = *(const bf16x8*)&buf[(ch * 8 + h * 4 + j) * 512 + g * 128 + fr * 8];
            #pragma unroll
            for (int j = 0; j < 4; ++j) {
                acc[0][h * 4 + j] = __builtin_amdgcn_mfma_f32_16x16x32_bf16(a[0], bfr[j], acc[0][h * 4 + j], 0, 0, 0);
                acc[1][h * 4 + j] = __builtin_amdgcn_mfma_f32_16x16x32_bf16(a[1], bfr[j], acc[1][h * 4 + j], 0, 0, 0);
            }
        }
        #pragma unroll
        for (int af = 0; af < 2; ++af) a[af] = na[af];
    }

    // ---- epilogue: per-row sum of exp2 over this wave's 128 cols (no max) ----
    // C/D layout: col = ch*128 + mt*16 + (lane&15), row = rh*32 + af*16 + (lane>>4)*4 + reg
    constexpr float INV_TAU_LN2 = 0.7213475204444817f;  // 1/(tau*ln2), tau=2
    constexpr float TAU_LN2     = 1.3862943611198906f;  // tau*ln2
    const int q4 = (lane >> 4) * 4;

    #pragma unroll
    for (int af = 0; af < 2; ++af) {
        #pragma unroll
        for (int r = 0; r < 4; ++r) {
            float s2 = 0.f;
            #pragma unroll
            for (int mt = 0; mt < 8; ++mt)
                s2 += exp2f(acc[af][mt][r] * INV_TAU_LN2);
            #pragma unroll
            for (int m = 1; m < 16; m <<= 1)
                s2 += __shfl_xor(s2, m, 64);
            if (fr == 0)
                ms[rh * 32 + af * 16 + q4 + r][ch] = s2;
        }
    }
    __syncthreads();

    // merge col-halves + lse + block-sum: wave 0, one lane per row
    if (tid < 64) {
        float s = ms[tid][0] + ms[tid][1];
        float lse = TAU_LN2 * log2f(s);
        #pragma unroll
        for (int d = 1; d < 64; d <<= 1) lse += __shfl_xor(lse, d, 64);
        if (tid == 0)
            atomicAdd(&out[bi * 32 + bj], lse * (1.0f / Na));
    }
}

extern "C" void kernel_launch(void* const* d_in, const int* in_sizes, int n_in,
                              void* d_out, int out_size, void* d_ws, size_t ws_size,
                              hipStream_t stream) {
    const float* audio  = (const float*)d_in[0];
    const float* visual = (const float*)d_in[1];
    float* out = (float*)d_out;

    unsigned short* asw = (unsigned short*)d_ws;                 // 12.58 MB swizzled A
    unsigned short* bsw = asw + (size_t)AUNITS * 8;              // +6.29 MB swizzled B

    convert_swizzle_kernel<<<dim3((TUNITS + 255) / 256), dim3(256), 0, stream>>>(
        audio, visual, asw, bsw, out);
    gemm_lse_kernel<<<dim3(B_ * B_ * NCH), dim3(256), 0, stream>>>(asw, bsw, out);
}